// Round 7
// baseline (111.694 us; speedup 1.0000x reference)
//
#include <hip/hip_runtime.h>

// CenterLoss, closed form (clamp provably inactive for these inputs:
// pairwise sq-dists are 4096 +- ~130, far inside [1e-12,1e12]; absmax=0
// verified rounds 1-6):
//   Sum_all  = C*Sx + B*Sc - 2*S2,  S2 = sum_b (x_b . sc), sc = colsum(centers)
//   Sum_diag = Sx + Scl - 2*Sdot
//   loss = Sum_diag/B - 0.001*(Sum_all - Sum_diag)/(B*(C-1))
//
// Round-6 post-mortem: harness fixed cost (268 MB ws poison fill ~41 us +
// input restore ~23 us) dominates dur_us; our budget is x_kernel. This round
// decouples the gather stream from the x stream: all 8 gathered center rows
// load up front (independent, L2/L3-hot — centers are 8 MB, fully cache
// resident), scl computed eagerly, main loop is pure x streaming (depth-2).
// Zero atomics (round-3), no big intermediates (round-4), VGPR kept <=64
// for the 8-waves/SIMD cliff.

#define DD 2048
#define NB 8192
#define NC 1000
#define D4 (DD / 4)            // 512 float4 per row
#define HALF4 256              // float4 per half-row
#define THREADS 256
#define XROWS 8
#define XBLOCKS ((NB / XROWS) * 2)   // 2048: row-group x column-half
#define CTILES 8
#define CRG 8
#define CBLOCKS (CTILES * CRG)       // 64

// ws layout (bytes):
//   cq  [CRG][2048] f32  @ 0      (64 KB)  centers colsum partial rows
//   sc  [2048]      f32  @ 65536  (8 KB)   final centers colsum
//   csq [CBLOCKS]   f32  @ 73728  (256 B)  per-block Sc partials
//   part[XBLOCKS] float4 @ 73984  (32 KB)  per-x-block {sx, sdot, scl, s2}
#define CQ_OFF   0
#define SC_OFF   65536
#define CSQ_OFF  73728
#define PART_OFF 73984

__device__ __forceinline__ float dot4(float4 a, float4 b) {
    return a.x * b.x + a.y * b.y + a.z * b.z + a.w * b.w;
}
__device__ __forceinline__ void acc4(float4& a, float4 b) {
    a.x += b.x; a.y += b.y; a.z += b.z; a.w += b.w;
}

// Kernel 1: centers -> cq (8 partial colsum rows) + csq partials.
// 64 blocks = 8 col-tiles x 8 row-groups of 125 rows.
__global__ __launch_bounds__(THREADS) void centers_kernel(
        const float4* __restrict__ c4, float4* __restrict__ cq,
        float* __restrict__ csq_part) {
    const int t = threadIdx.x;
    const int tile = blockIdx.x & (CTILES - 1);
    const int rg = blockIdx.x >> 3;
    const int col4 = tile * 64 + (t & 63);
    const int rlane = t >> 6;                 // 0..3
    const int row0 = rg * 125;

    float4 acc = make_float4(0.f, 0.f, 0.f, 0.f);
    float csq = 0.f;
#pragma unroll 8
    for (int r = rlane; r < 125; r += 4) {
        float4 v = c4[(size_t)(row0 + r) * D4 + col4];
        acc4(acc, v);
        csq += dot4(v, v);
    }

    __shared__ float4 lds[4][64];
    lds[rlane][t & 63] = acc;
    __syncthreads();
    if (t < 64) {
        float4 s = lds[0][t];
        acc4(s, lds[1][t]); acc4(s, lds[2][t]); acc4(s, lds[3][t]);
        cq[rg * 512 + tile * 64 + t] = s;
    }

    __shared__ float red[THREADS / 64];
    for (int off = 32; off > 0; off >>= 1) csq += __shfl_down(csq, off, 64);
    const int lane = t & 63, wv = t >> 6;
    if (lane == 0) red[wv] = csq;
    __syncthreads();
    if (t == 0)
        csq_part[blockIdx.x] = red[0] + red[1] + red[2] + red[3];
}

// Kernel 2: fold cq[8][2048] -> sc[2048]. 2 blocks x 256 threads.
__global__ __launch_bounds__(THREADS) void sc_fold_kernel(
        const float4* __restrict__ cq, float4* __restrict__ sc4) {
    const int idx = blockIdx.x * THREADS + threadIdx.x;   // 0..511
    float4 s = cq[idx];
#pragma unroll
    for (int r = 1; r < CRG; ++r) acc4(s, cq[r * 512 + idx]);
    sc4[idx] = s;
}

// Kernel 3: x -> {sx, sdot, scl, s2} per block. 2048 blocks: row-group
// (8 rows) x column-half (1024 cols). All 8 gathered center rows load up
// front (L2/L3-hot); main loop is pure x streaming with depth-2 pipeline.
__global__ __launch_bounds__(THREADS) void x_kernel(
        const float4* __restrict__ x4, const float4* __restrict__ c4,
        const int* __restrict__ labels, const float4* __restrict__ sc4,
        float4* __restrict__ partials) {
    const int t = threadIdx.x;
    const int b = blockIdx.x;
    const int rowgrp = b >> 1;
    const int h = (b & 1) * HALF4;          // float4 offset of this half
    const int rows0 = rowgrp * XROWS;

    int labs[XROWS];
#pragma unroll
    for (int r = 0; r < XROWS; ++r) labs[r] = labels[rows0 + r];  // uniform

    // start the x stream first (HBM, long latency)
    const float4* xr = x4 + (size_t)rows0 * D4 + h + t;
    float4 xa = xr[0];
    float4 xb = xr[D4];

    // all 8 gathered center rows in flight (cache-hot)
    const float4* cbase = c4 + h + t;
    float4 cr[XROWS];
#pragma unroll
    for (int r = 0; r < XROWS; ++r) cr[r] = cbase[(size_t)labs[r] * D4];

    const float4 sc = sc4[h + t];

    // scl does not involve x — fold it eagerly
    float scl = 0.f;
#pragma unroll
    for (int r = 0; r < XROWS; ++r) scl += dot4(cr[r], cr[r]);

    float sx = 0.f, sdot = 0.f, s2 = 0.f;
#pragma unroll
    for (int r = 0; r < XROWS; ++r) {
        float4 nx;
        if (r + 2 < XROWS) nx = xr[(size_t)(r + 2) * D4];
        sx   += dot4(xa, xa);
        sdot += dot4(xa, cr[r]);
        s2   += dot4(xa, sc);
        xa = xb;
        if (r + 2 < XROWS) xb = nx;
    }

    __shared__ float red[4][THREADS / 64];
    for (int off = 32; off > 0; off >>= 1) {
        sx   += __shfl_down(sx, off, 64);
        sdot += __shfl_down(sdot, off, 64);
        scl  += __shfl_down(scl, off, 64);
        s2   += __shfl_down(s2, off, 64);
    }
    const int lane = t & 63, wv = t >> 6;
    if (lane == 0) {
        red[0][wv] = sx; red[1][wv] = sdot;
        red[2][wv] = scl; red[3][wv] = s2;
    }
    __syncthreads();
    if (t == 0) {
        float4 s;
        s.x = red[0][0] + red[0][1] + red[0][2] + red[0][3];
        s.y = red[1][0] + red[1][1] + red[1][2] + red[1][3];
        s.z = red[2][0] + red[2][1] + red[2][2] + red[2][3];
        s.w = red[3][0] + red[3][1] + red[3][2] + red[3][3];
        partials[b] = s;
    }
}

__global__ __launch_bounds__(THREADS) void finalize_kernel(
        const float4* __restrict__ partials, const float* __restrict__ csq_part,
        float* __restrict__ out) {
    const int t = threadIdx.x;

    double sx = 0.0, sdot = 0.0, scl = 0.0, s2 = 0.0, csq = 0.0;
    for (int i = t; i < XBLOCKS; i += THREADS) {
        float4 p = partials[i];
        sx += (double)p.x; sdot += (double)p.y;
        scl += (double)p.z; s2 += (double)p.w;
    }
    if (t < CBLOCKS) csq = (double)csq_part[t];

    __shared__ double red[5][THREADS / 64];
    for (int off = 32; off > 0; off >>= 1) {
        sx   += __shfl_down(sx, off, 64);
        sdot += __shfl_down(sdot, off, 64);
        scl  += __shfl_down(scl, off, 64);
        s2   += __shfl_down(s2, off, 64);
        csq  += __shfl_down(csq, off, 64);
    }
    const int lane = t & 63, wv = t >> 6;
    if (lane == 0) {
        red[0][wv] = sx; red[1][wv] = sdot; red[2][wv] = scl;
        red[3][wv] = s2; red[4][wv] = csq;
    }
    __syncthreads();
    if (t == 0) {
        double Sx   = red[0][0] + red[0][1] + red[0][2] + red[0][3];
        double Sdot = red[1][0] + red[1][1] + red[1][2] + red[1][3];
        double Scl  = red[2][0] + red[2][1] + red[2][2] + red[2][3];
        double S2   = red[3][0] + red[3][1] + red[3][2] + red[3][3];
        double Sc   = red[4][0] + red[4][1] + red[4][2] + red[4][3];
        double sum_all  = (double)NC * Sx + (double)NB * Sc - 2.0 * S2;
        double sum_diag = Sx + Scl - 2.0 * Sdot;
        double center_loss = sum_diag / (double)NB;
        double sep_loss =
            (sum_all - sum_diag) / ((double)NB * (double)(NC - 1));
        out[0] = (float)(center_loss - 0.001 * sep_loss);
    }
}

extern "C" void kernel_launch(void* const* d_in, const int* in_sizes, int n_in,
                              void* d_out, int out_size, void* d_ws, size_t ws_size,
                              hipStream_t stream) {
    const float4* x4 = (const float4*)d_in[0];   // [8192, 2048] f32
    const float4* c4 = (const float4*)d_in[1];   // [1000, 2048] f32
    const int* labels = (const int*)d_in[2];     // [8192] i32

    float4* cq = (float4*)((char*)d_ws + CQ_OFF);
    float4* sc = (float4*)((char*)d_ws + SC_OFF);
    float* csq_part = (float*)((char*)d_ws + CSQ_OFF);
    float4* partials = (float4*)((char*)d_ws + PART_OFF);
    float* out = (float*)d_out;

    centers_kernel<<<CBLOCKS, THREADS, 0, stream>>>(c4, cq, csq_part);
    sc_fold_kernel<<<2, THREADS, 0, stream>>>((const float4*)cq, sc);
    x_kernel<<<XBLOCKS, THREADS, 0, stream>>>(x4, c4, labels,
                                              (const float4*)sc, partials);
    finalize_kernel<<<1, THREADS, 0, stream>>>(partials, csq_part, out);
}